// Round 6
// baseline (183.016 us; speedup 1.0000x reference)
//
#include <hip/hip_runtime.h>
#include <stdint.h>

// Moment features: all monomials of degree <= 4 over 16 latent dims.
// Output [8192, 4845] fp32 (~158.8 MB) -> HBM-write-bound (~27 us floor).
//
// r1-r5 finding: kernel pinned at ~65 us (2.44 TB/s) across radically
// different issue structures; NT stores -25%; conflict-free LDS no change;
// register-pipelined stores no change => memory-side limit, and the one
// invariant was 2048 concurrent per-block write streams (~16/HBM channel,
// DRAM row thrash). This version: 16 rows per block, grid 512 -> 512
// streams (~4/channel), each a contiguous 310KB sweep. LDS = 16x969 floats
// (62KB, 2 blocks/CU). Store table stays the compact 4-row version; runtime
// q/4845 picks the 4-row subgroup, packed byte-offset add relocates both
// operands (no cross-half carry: max 61996 < 65536).

#define D       16
#define NC      4845          // 1 + 16 + 136 + 816 + 3876 = C(20,4)
#define POSPB   16            // rows per block
#define SUBROWS 4             // rows per table subgroup
#define SUBCH   4845          // 16B chunks per 4-row subgroup (4*4845/4)
#define NPAD2   4928          // table chunks incl. pad (covers qq<=4920)
#define GCHUNK  19380         // chunks per 16-row group (16*4845/4)
#define GITER   76            // store iterations (76*256 = 19456 >= GCHUNK)
#define STRIDE  969           // LDS floats/row: 1.0, x[16], o2[136], o3[816]
#define SUBB    15504u        // bytes per 4-row subgroup image (4*969*4)

typedef float    f4_t __attribute__((ext_vector_type(4)));
typedef uint32_t u4_t __attribute__((ext_vector_type(4)));

struct alignas(16) Tables {
    uint32_t chunk[NPAD2 * 4]; // per dword of a 4-row subgroup: byte offs
                               // (p*969+A)*4 | ((p*969+B)*4)<<16 ; pad = 0
};

static constexpr Tables build_tables() {
    Tables t{};
    // ---- per-channel (A = prefix slot, B = x slot), reference order ----
    unsigned short A[NC] = {}, B[NC] = {};
    int pos = 0;
    A[pos] = 0; B[pos] = 0; ++pos;                        // ones: 1*1
    for (int i = 0; i < D; ++i) { A[pos] = 0; B[pos] = (unsigned short)(1 + i); ++pos; }
    long c[D] = {};
    for (int i = 0; i < D; ++i) c[i] = 1;
    int baseprev = 1;
    const int basecur[3] = {17, 153, 969};
    for (int it = 0; it < 3; ++it) {
        long S[D] = {};
        long acc = 0;
        for (int i = D - 1; i >= 0; --i) { acc += c[i]; S[i] = acc; }
        const long n = S[0];
        long off[D] = {};
        for (int i = 0; i < D; ++i) off[i] = n - S[i];
        for (long k = 0; k < n; ++k)                      // np.nonzero row-major
            for (int j = 0; j < D; ++j)
                if (k >= off[j]) {
                    A[pos] = (unsigned short)(baseprev + (int)k);
                    B[pos] = (unsigned short)(1 + j);
                    ++pos;
                }
        baseprev = basecur[it];
        for (int i = 0; i < D; ++i) c[i] = S[i];
    }
    // ---- flat dword table for one 4-row subgroup, byte offsets ----
    for (int f = 0; f < NPAD2 * 4; ++f) {
        const int p = f / NC;
        const int ch = f - p * NC;
        if (p < SUBROWS)
            t.chunk[f] = (uint32_t)((p * STRIDE + A[ch]) * 4)
                       | ((uint32_t)((p * STRIDE + B[ch]) * 4) << 16);
        else
            t.chunk[f] = 0;   // pad: reads lds[0]*lds[0]; store masked off
    }
    return t;
}

__device__ const Tables d_tables = build_tables();

__global__ __launch_bounds__(256) void moment_kernel(const float* __restrict__ in,
                                                     float* __restrict__ out) {
    __shared__ float lds[POSPB * STRIDE];   // 62016 B -> 2 blocks/CU
    const int tid = threadIdx.x;
    const int blk = blockIdx.x;
    const uint32_t* __restrict__ dtab = d_tables.chunk;
    const u4_t* __restrict__ tab4 = (const u4_t*)dtab;

    // ---- stage x: 16 rows * 16 floats (one float/thread, coalesced) + ones
    lds[(tid >> 4) * STRIDE + 1 + (tid & 15)] = in[(size_t)blk * (POSPB * D) + tid];
    if (tid < POSPB) lds[tid * STRIDE] = 1.0f;
    __syncthreads();

    // ---- order-2 feats: 136 x 16 rows (x[k]*x[j], reference association)
    for (int i = tid; i < 136 * POSPB; i += 256) {
        const int ch = 17 + (i >> 4);
        const int po = (i & 15) * STRIDE;
        const uint32_t t = dtab[ch];                  // row-0 entry: byte offs
        lds[po + ((t & 0xFFFFu) >> 2)] * 1.0f;        // (no-op guard removed)
        lds[po + ch] = lds[po + ((t & 0xFFFFu) >> 2)] * lds[po + (t >> 18)];
    }
    __syncthreads();

    // ---- order-3 feats: 816 x 16 rows (prev * x, reference association)
    for (int i = tid; i < 816 * POSPB; i += 256) {
        const int ch = 153 + (i >> 4);
        const int po = (i & 15) * STRIDE;
        const uint32_t t = dtab[ch];
        lds[po + ch] = lds[po + ((t & 0xFFFFu) >> 2)] * lds[po + (t >> 18)];
    }
    __syncthreads();

    // ---- store phase: contiguous 310KB sweep per block, coalesced dwordx4
    f4_t* __restrict__ ochunk = (f4_t*)(out + (size_t)blk * (size_t)(POSPB * NC));
    const char* __restrict__ lb = (const char*)lds;
    #pragma unroll 4
    for (int i = 0; i < GITER; ++i) {
        const int q = tid + i * 256;                 // 0 .. 19455
        unsigned sub = (unsigned)q / (unsigned)SUBCH; // magic-mul div
        if (sub > 3u) sub = 3u;
        const int qq = q - (int)(sub * (unsigned)SUBCH);   // 0 .. 4920 < NPAD2
        const u4_t e = tab4[qq];
        const unsigned addp = sub * (SUBB | (SUBB << 16)); // relocate both halves
        const unsigned ex = e.x + addp, ey = e.y + addp;
        const unsigned ez = e.z + addp, ew = e.w + addp;
        f4_t v;
        v.x = *(const float*)(lb + (ex & 0xFFFFu)) * *(const float*)(lb + (ex >> 16));
        v.y = *(const float*)(lb + (ey & 0xFFFFu)) * *(const float*)(lb + (ey >> 16));
        v.z = *(const float*)(lb + (ez & 0xFFFFu)) * *(const float*)(lb + (ez >> 16));
        v.w = *(const float*)(lb + (ew & 0xFFFFu)) * *(const float*)(lb + (ew >> 16));
        if (q < GCHUNK) ochunk[q] = v;
    }
}

extern "C" void kernel_launch(void* const* d_in, const int* in_sizes, int n_in,
                              void* d_out, int out_size, void* d_ws, size_t ws_size,
                              hipStream_t stream) {
    const float* in = (const float*)d_in[0];
    float* out = (float*)d_out;
    const int npos = in_sizes[0] / D;        // 8192
    const int nblk = npos / POSPB;           // 512
    moment_kernel<<<nblk, 256, 0, stream>>>(in, out);
}